// Round 1
// baseline (308.581 us; speedup 1.0000x reference)
//
#include <hip/hip_runtime.h>

constexpr int DEG   = 31;   // neighbors per node
constexpr int NEV   = 32;   // events per node (self + neighbors)
constexpr int TH    = 16;   // threshold: track dp[0..15] + absorbing "over"
constexpr int BLK   = 256;

__global__ void zero_out_kernel(float* out) {
    if (threadIdx.x == 0) out[0] = 0.0f;
}

__device__ __forceinline__ float fast_sigmoid(float x) {
    return 1.0f / (1.0f + __expf(-x));
}

__global__ __launch_bounds__(BLK)
void pgl_kernel(const float* __restrict__ gains,
                const int*   __restrict__ nbr,
                float*       __restrict__ out,
                int n) {
    __shared__ int s_idx[BLK * DEG];          // 31744 B
    __shared__ float s_red[BLK / 64];

    const int tid        = threadIdx.x;
    const int blockStart = blockIdx.x * BLK;

    // ---- stage this block's neighbor rows into LDS, coalesced ----
    // base element offset = blockStart*31; blockStart is a multiple of 256,
    // so byte offset is a multiple of 256*31*4 -> 16B-aligned: int4 loads OK.
    const int rows  = min(BLK, n - blockStart);
    const int elems = rows * DEG;
    const int base  = blockStart * DEG;

    const int4* nb4 = (const int4*)(nbr + base);
    int4*       s4  = (int4*)s_idx;
    const int nvec  = elems >> 2;
    for (int v = tid; v < nvec; v += BLK) s4[v] = nb4[v];
    for (int e = (nvec << 2) + tid; e < elems; e += BLK) s_idx[e] = nbr[base + e];
    __syncthreads();

    // ---- per-node absorbing-state Poisson-binomial DP ----
    float local = 0.0f;
    const int i = blockStart + tid;
    if (i < n) {
        const int* row = s_idx + tid * DEG;  // LDS stride 31 -> conflict-free (2-way alias only)

        float dp[TH];
        dp[0] = 1.0f;
        #pragma unroll
        for (int k = 1; k < TH; ++k) dp[k] = 0.0f;
        float over = 0.0f;

        const float p0 = fast_sigmoid(gains[i]);

        #pragma unroll
        for (int j = 0; j < NEV; ++j) {
            float pj;
            if (j == 0) {
                pj = p0;
            } else {
                const int idx = row[j - 1];
                pj = fast_sigmoid(gains[idx]);   // random gather, L2-resident table
            }
            // absorb mass that reaches count==16 (only possible once j >= 15)
            if (j >= TH - 1) over = fmaf(dp[TH - 1], pj, over);
            const int kmax = (j + 1 < TH - 1) ? (j + 1) : (TH - 1);
            #pragma unroll
            for (int k = kmax; k >= 1; --k)
                dp[k] = fmaf(pj, dp[k - 1] - dp[k], dp[k]);
            dp[0] = fmaf(-pj, dp[0], dp[0]);
        }
        // contribution to -(loss): 0.25*p - P(count>=16)
        local = fmaf(0.25f, p0, -over);
    }

    // ---- block reduction: wave shuffle -> LDS -> one atomic per block ----
    #pragma unroll
    for (int off = 32; off > 0; off >>= 1)
        local += __shfl_down(local, off, 64);
    if ((tid & 63) == 0) s_red[tid >> 6] = local;
    __syncthreads();
    if (tid == 0) {
        float s = 0.0f;
        #pragma unroll
        for (int w = 0; w < BLK / 64; ++w) s += s_red[w];
        atomicAdd(out, s);
    }
}

extern "C" void kernel_launch(void* const* d_in, const int* in_sizes, int n_in,
                              void* d_out, int out_size, void* d_ws, size_t ws_size,
                              hipStream_t stream) {
    const float* gains = (const float*)d_in[0];
    const int*   nbr   = (const int*)d_in[1];
    float*       out   = (float*)d_out;
    const int n = in_sizes[0];

    zero_out_kernel<<<1, 64, 0, stream>>>(out);
    const int grid = (n + BLK - 1) / BLK;
    pgl_kernel<<<grid, BLK, 0, stream>>>(gains, nbr, out, n);
}